// Round 18
// baseline (224.847 us; speedup 1.0000x reference)
//
#include <hip/hip_runtime.h>
#include <stdint.h>

// Problem constants (from reference setup_inputs)
#define M_TOK 8192
#define N_OUT 4096
#define K_IN  4096

// INT8 GEMM, 32x32x32 MFMA (4404 TOPS ubench vs 3944 for 16x16x64).
// 256x256 tile, BK=128, double-buffered LDS (128 KiB), 8 waves 2x4.
// R14's verified 4-phase single-sync skeleton; only frag shape + LDS layout
// changed. W is EXACTLY int8; x per-token int8 (sx = rowmax/127); exact i32
// accumulation -> absmax identical to R14 (4.5).
#define BM 256
#define BN 256
#define BK 128
#define NT (K_IN / BK)            // 32 K-tiles
#define SLICE 8192                // bytes per k-slice section (256 rows x 32 B)
#define BSEC  32768               // B section offset within buffer
#define BUF   65536               // bytes per buffer (A 4 slices | B 4 slices)

typedef int intx4  __attribute__((ext_vector_type(4)));
typedef int intx16 __attribute__((ext_vector_type(16)));

#define MFMA32 __builtin_amdgcn_mfma_i32_32x32x32_i8

// ---------- helpers ----------

// async global->LDS, 16 bytes per lane. LDS side is wave-uniform base + lane*16.
__device__ __forceinline__ void async_copy16(const void* g, void* l) {
    __builtin_amdgcn_global_load_lds(
        (__attribute__((address_space(1))) void*)(g),
        (__attribute__((address_space(3))) void*)(l),
        16, 0, 0);
}

// ---------- fused pre-pass: x fp32 -> int8 per-token AND W int32 -> int8 ----------
// Blocks [0, M_TOK): quantize one x row each (sx = rowmax/127, RNE).
// Blocks [M_TOK, M_TOK + NWB): pack 16 W elements per thread (EXACT).

#define NWB 4096   // W-pack blocks: (N_OUT*K_IN/16) / 256

__global__ void prep_kernel(const float* __restrict__ x,
                            const int* __restrict__ wq,
                            int8_t* __restrict__ xq,
                            float* __restrict__ sx,
                            int8_t* __restrict__ wb) {
    const int tid = threadIdx.x;

    if (blockIdx.x < M_TOK) {
        // ---- x row quantization ----
        const int row = blockIdx.x;
        const float4* p = (const float4*)(x + (size_t)row * K_IN + tid * 16);
        float4 v0 = p[0], v1 = p[1], v2 = p[2], v3 = p[3];

        float m = fabsf(v0.x);
        m = fmaxf(m, fabsf(v0.y)); m = fmaxf(m, fabsf(v0.z)); m = fmaxf(m, fabsf(v0.w));
        m = fmaxf(m, fabsf(v1.x)); m = fmaxf(m, fabsf(v1.y));
        m = fmaxf(m, fabsf(v1.z)); m = fmaxf(m, fabsf(v1.w));
        m = fmaxf(m, fabsf(v2.x)); m = fmaxf(m, fabsf(v2.y));
        m = fmaxf(m, fabsf(v2.z)); m = fmaxf(m, fabsf(v2.w));
        m = fmaxf(m, fabsf(v3.x)); m = fmaxf(m, fabsf(v3.y));
        m = fmaxf(m, fabsf(v3.z)); m = fmaxf(m, fabsf(v3.w));

#pragma unroll
        for (int off = 32; off; off >>= 1) m = fmaxf(m, __shfl_xor(m, off));
        __shared__ float wmax[4];
        if ((tid & 63) == 0) wmax[tid >> 6] = m;
        __syncthreads();
        m = fmaxf(fmaxf(wmax[0], wmax[1]), fmaxf(wmax[2], wmax[3]));
        m = fmaxf(m, 1e-20f);

        const float rs = 127.0f / m;
        if (tid == 0) sx[row] = m * (1.0f / 127.0f);

        union { int4 v; int8_t c[16]; } u;
        u.c[0]  = (int8_t)__float2int_rn(v0.x * rs);
        u.c[1]  = (int8_t)__float2int_rn(v0.y * rs);
        u.c[2]  = (int8_t)__float2int_rn(v0.z * rs);
        u.c[3]  = (int8_t)__float2int_rn(v0.w * rs);
        u.c[4]  = (int8_t)__float2int_rn(v1.x * rs);
        u.c[5]  = (int8_t)__float2int_rn(v1.y * rs);
        u.c[6]  = (int8_t)__float2int_rn(v1.z * rs);
        u.c[7]  = (int8_t)__float2int_rn(v1.w * rs);
        u.c[8]  = (int8_t)__float2int_rn(v2.x * rs);
        u.c[9]  = (int8_t)__float2int_rn(v2.y * rs);
        u.c[10] = (int8_t)__float2int_rn(v2.z * rs);
        u.c[11] = (int8_t)__float2int_rn(v2.w * rs);
        u.c[12] = (int8_t)__float2int_rn(v3.x * rs);
        u.c[13] = (int8_t)__float2int_rn(v3.y * rs);
        u.c[14] = (int8_t)__float2int_rn(v3.z * rs);
        u.c[15] = (int8_t)__float2int_rn(v3.w * rs);
        ((int4*)(xq + (size_t)row * K_IN))[tid] = u.v;
    } else {
        // ---- W pack: int32 (int8-valued) -> int8, exact ----
        const int i = (blockIdx.x - M_TOK) * 256 + tid;   // 16 elements each
        const int4* p = (const int4*)wq + (size_t)i * 4;
        int4 a = p[0], b = p[1], c = p[2], d = p[3];
        union { int4 v; int8_t q[16]; } u;
        u.q[0]  = (int8_t)a.x; u.q[1]  = (int8_t)a.y; u.q[2]  = (int8_t)a.z; u.q[3]  = (int8_t)a.w;
        u.q[4]  = (int8_t)b.x; u.q[5]  = (int8_t)b.y; u.q[6]  = (int8_t)b.z; u.q[7]  = (int8_t)b.w;
        u.q[8]  = (int8_t)c.x; u.q[9]  = (int8_t)c.y; u.q[10] = (int8_t)c.z; u.q[11] = (int8_t)c.w;
        u.q[12] = (int8_t)d.x; u.q[13] = (int8_t)d.y; u.q[14] = (int8_t)d.z; u.q[15] = (int8_t)d.w;
        ((int4*)wb)[i] = u.v;
    }
}

// ---------- GEMM: C[m][n] = sx[m]*scales[n]*(sum_k xq*wq) + bias[n] ----------
// mfma_i32_32x32x32_i8: A row = lane&31, k = (lane>>5)*16 + j (4 VGPR = 16 B);
// B symmetric from [N][K]; C/D col = lane&31, row = (reg&3)+8*(reg>>2)+
// 4*(lane>>5) -- all three mappings correctness-verified in R5 (its failure
// was banks, not math). Per wave per BK=128 tile: 24 ds_read_b128 + 32 MFMA.
//
// LDS (the R5 bank fix): k-slice-major. Per buffer: A = 4 slices x 8
// row-group WINDOWS of 1 KiB (32 rows x 32 B), then B likewise. Within a
// window, 16-B chunk (r, c) stored at c' = c ^ ((r>>2)&1). Enumerated: each
// frag read's 64 lanes cover the window's 1 KiB exactly once; position
// (r%4)*2+c' holds 8 lanes spread over 8 distinct 128-B slots (r>>2) ->
// CONFLICT-FREE. Inverse swizzle on the per-lane GLOBAL source; linear LDS
// dest (1 global_load_lds issue = 1 slice = 8 KiB).
//
// Ledger (verbatim R14; DS in-order per wave; stage = 4+4 gloads in P1/P2):
//  P1: stage A(t+1) x4 | read A23,sp0 (4) | lgkm(4) [drains prev 8] |
//      MM01(afA,bfA)  [8 MFMA, slice-pair 0]
//  P2: stage B(t+1) x4 | read A01,sp1 + B,sp1 (8) | lgkm(8) | MM23(afB,bfA)
//  P3: read A23,sp1 (4) | lgkm(4) | MM01(afA,bfB)
//  P4: vmcnt(0)+lgkm(0) [stages issued 2-3 phases earlier, latency-covered
//      (R16: counted vmcnt gains nothing here)] | BARRIER | read next
//      A01,sp0 + B,sp0 (8) | MM23(afB,bfB)
// Hazards identical to R14 (verified): all buf(t) reads lgkm-drained before
// the boundary barrier; stage(t+2) issues after it; buf(t+1) reads follow
// every wave's vmcnt(0)+barrier.

__global__ __launch_bounds__(512, 2)
void gemm_i8_kernel(const int8_t* __restrict__ A,
                    const int8_t* __restrict__ B,
                    const float* __restrict__ sx,
                    const float* __restrict__ scales,
                    const float* __restrict__ bias,
                    float* __restrict__ C) {
    __shared__ __align__(16) int8_t lds[2 * BUF];   // 128 KiB

    const int tid = threadIdx.x;

    // T1: bijective XCD swizzle (nwg = 512, divisible by 8), bn-fastest.
    const int nwg = (M_TOK / BM) * (N_OUT / BN);   // 32*16 = 512
    const int cpx = nwg / 8;                        // 64
    const int wg  = (blockIdx.x % 8) * cpx + blockIdx.x / 8;
    const int bn  = wg & 15;                        // N_OUT/BN = 16
    const int bm  = wg >> 4;                        // 0..31

    const int lane = tid & 63;
    const int wave = tid >> 6;          // 0..7
    const int wm   = wave >> 2;         // 0..1 -> rows wm*128
    const int wn   = wave & 3;          // 0..3 -> cols wn*64

    // ---- staging addressing (inverse window swizzle on global source) ----
    // One issue = 512 lanes x 16 B = 8 KiB = one slice (256 rows x 32 B).
    // Linear dest tid*16 -> window g = tid>>6, row r = (tid>>1)&31, c' = tid&1.
    // Global k-chunk c = c' ^ ((r>>2)&1) = (tid&1) ^ ((tid>>3)&1).
    const int grow0 = ((tid >> 6) << 5) + ((tid >> 1) & 31);   // 0..255
    const int gc0   = (((tid & 1) ^ ((tid >> 3) & 1)) << 4);   // 0 or 16 bytes
    const int8_t* aP = A + (size_t)(bm * BM + grow0) * K_IN + gc0;
    const int8_t* bP = B + (size_t)(bn * BN + grow0) * K_IN + gc0;

    auto stA = [&](int tt, int s) {   // one slice: 1 global_load_lds
        async_copy16(aP + (size_t)tt * BK + s * 32,
                     &lds[(tt & 1) * BUF + s * SLICE + tid * 16]);
    };
    auto stB = [&](int tt, int s) {
        async_copy16(bP + (size_t)tt * BK + s * 32,
                     &lds[(tt & 1) * BUF + BSEC + s * SLICE + tid * 16]);
    };

    // ---- fragment read addressing ----
    // Within a 1 KiB window: lane l -> byte (l&31)*32 + ((l>>5 ^ (l>>2))&1)*16.
    const int aRd = ((lane & 31) << 5) + ((((lane >> 5) ^ (lane >> 2)) & 1) << 4);
    const int hi  = lane >> 5;          // 0..1 (k-chunk, and C/D row offset 4*hi)

    intx16 acc[4][2] = {};
    intx4 afA[4], afB[4], bfA[4], bfB[4];   // [frag*2 + slice-within-pair]

    // A frags fr in {f0, f0+1} of slice-pair sp -> dst[(fr-f0)*2+ss]
#define RD_A(dst, base, sp, f0)                                                \
    { _Pragma("unroll") for (int fr = 0; fr < 2; ++fr)                         \
        _Pragma("unroll") for (int ss = 0; ss < 2; ++ss)                       \
            dst[fr * 2 + ss] = *(const intx4*)((base) +                        \
                ((sp) * 2 + ss) * SLICE + (wm * 4 + (f0) + fr) * 1024 + aRd); }
    // B frags fc in {0,1} of slice-pair sp
#define RD_B(dst, base, sp)                                                    \
    { _Pragma("unroll") for (int fc = 0; fc < 2; ++fc)                         \
        _Pragma("unroll") for (int ss = 0; ss < 2; ++ss)                       \
            dst[fc * 2 + ss] = *(const intx4*)((base) + BSEC +                 \
                ((sp) * 2 + ss) * SLICE + (wn * 2 + fc) * 1024 + aRd); }
#define MM(af, bf, a0)                                                         \
    { __builtin_amdgcn_s_setprio(1);                                           \
      _Pragma("unroll") for (int fr = 0; fr < 2; ++fr)                         \
          _Pragma("unroll") for (int fc = 0; fc < 2; ++fc)                     \
              _Pragma("unroll") for (int ss = 0; ss < 2; ++ss)                 \
                  acc[(a0) + fr][fc] = MFMA32(af[fr * 2 + ss],                 \
                      bf[fc * 2 + ss], acc[(a0) + fr][fc], 0, 0, 0);           \
      __builtin_amdgcn_s_setprio(0); }
#define SBAR __builtin_amdgcn_sched_barrier(0)

    // ---- prologue: stage tile 0, publish, read sp0 frags (8 in flight) ----
    stA(0, 0); stA(0, 1); stA(0, 2); stA(0, 3);
    stB(0, 0); stB(0, 1); stB(0, 2); stB(0, 3);
    asm volatile("s_waitcnt vmcnt(0)" ::: "memory");
    __builtin_amdgcn_s_barrier();
    asm volatile("" ::: "memory");
    RD_A(afA, lds, 0, 0);
    RD_B(bfA, lds, 0);

#pragma unroll 1
    for (int t = 0; t < NT; ++t) {
        const int8_t* Lb  = lds + (t & 1) * BUF;
        const int8_t* Lb2 = lds + ((t + 1) & 1) * BUF;
        const bool pf = (t + 1 < NT);

        // ---- P1: stage A(t+1) | read A23 sp0 | MM(afA,bfA)->acc[0,1] ----
        if (pf) { stA(t + 1, 0); stA(t + 1, 1); stA(t + 1, 2); stA(t + 1, 3); }
        RD_A(afB, Lb, 0, 2);
        asm volatile("s_waitcnt lgkmcnt(4)" ::: "memory");
        SBAR;
        MM(afA, bfA, 0);

        // ---- P2: stage B(t+1) | read A01 sp1, B sp1 | MM(afB,bfA)->acc[2,3] ----
        if (pf) { stB(t + 1, 0); stB(t + 1, 1); stB(t + 1, 2); stB(t + 1, 3); }
        RD_A(afA, Lb, 1, 0);
        RD_B(bfB, Lb, 1);
        asm volatile("s_waitcnt lgkmcnt(8)" ::: "memory");
        SBAR;
        MM(afB, bfA, 2);

        // ---- P3: read A23 sp1 | MM(afA,bfB)->acc[0,1] ----
        RD_A(afB, Lb, 1, 2);
        asm volatile("s_waitcnt lgkmcnt(4)" ::: "memory");
        SBAR;
        MM(afA, bfB, 0);

        // ---- P4: boundary sync | read next sp0 frags | MM(afB,bfB)->acc[2,3] ----
        asm volatile("s_waitcnt vmcnt(0) lgkmcnt(0)" ::: "memory");
        __builtin_amdgcn_s_barrier();
        asm volatile("" ::: "memory");
        if (pf) {
            RD_A(afA, Lb2, 0, 0);
            RD_B(bfA, Lb2, 0);
        }
        SBAR;
        MM(afB, bfB, 2);
    }

    // ---- epilogue: C/D col = lane&31, row = (reg&3)+8*(reg>>2)+4*hi ----
    const int row0 = bm * BM + wm * 128 + 4 * hi;
    const int col0 = bn * BN + wn * 64 + (lane & 31);
#pragma unroll
    for (int fc = 0; fc < 2; ++fc) {
        const int n  = col0 + fc * 32;
        const float sc = scales[n];
        const float bi = bias[n];
#pragma unroll
        for (int fr = 0; fr < 4; ++fr) {
            const int mb = row0 + fr * 32;
#pragma unroll
            for (int reg = 0; reg < 16; ++reg) {
                const int m = mb + (reg & 3) + 8 * (reg >> 2);
                C[(size_t)m * N_OUT + n] =
                    (float)acc[fr][fc][reg] * (sx[m] * sc) + bi;
            }
        }
    }
}

// ---------- launch ----------

extern "C" void kernel_launch(void* const* d_in, const int* in_sizes, int n_in,
                              void* d_out, int out_size, void* d_ws, size_t ws_size,
                              hipStream_t stream) {
    const float* x      = (const float*)d_in[0];
    const int*   wq     = (const int*)d_in[1];
    const float* scales = (const float*)d_in[2];
    const float* bias   = (const float*)d_in[3];
    float*       out    = (float*)d_out;

    int8_t* xq = (int8_t*)d_ws;                               // 32 MiB
    int8_t* wb = xq + (size_t)M_TOK * K_IN;                   // 16 MiB
    float*  sx = (float*)(wb + (size_t)N_OUT * K_IN);         // 32 KiB
    // ws needed: 48 MiB + 32 KiB

    // Fused prepass: blocks [0,8192) quantize x rows; [8192,12288) pack W.
    prep_kernel<<<M_TOK + NWB, 256, 0, stream>>>(x, wq, xq, sx, wb);

    const int grid = (M_TOK / BM) * (N_OUT / BN);   // 32 * 16 = 512
    gemm_i8_kernel<<<grid, 512, 0, stream>>>(xq, wb, sx, scales, bias, out);
}

// Round 19
// 187.491 us; speedup vs baseline: 1.1992x; 1.1992x over previous
//
#include <hip/hip_runtime.h>
#include <stdint.h>

// Problem constants (from reference setup_inputs)
#define M_TOK 8192
#define N_OUT 4096
#define K_IN  4096

// INT8 GEMM: 256x256 tile, BK=128, double-buffered LDS (128 KiB), 8 waves 2x4.
// W is EXACTLY int8 (reference stores int8 values in int32); x quantized
// per-token to int8 (sx = rowmax/127). Inner product exact in int32.
// SESSION-BEST configuration (R14: total 187.8us, gemm ~140us, absmax 4.5).
// Full lever map closed: wait-retiming (R6/R7/R16 neutral), role-split
// (R10/R11 spill), 128x128 wave-tiles (R15 spill), B-direct-global (R13
// worse), 32x32 MFMA (R5/R18 bank-conflicted), 2-block/CU (R8 worse),
// prepass fusion (R17 neutral). Only the 16x16 pair-row pattern measures
// 0 LDS bank conflicts on this hardware.
#define BM 256
#define BN 256
#define BK 128
#define NT (K_IN / BK)            // 32 K-tiles
#define SEC 16384                 // bytes per k-slice section (256 rows x 64 B)
#define BUF 65536                 // bytes per buffer (A_s0|A_s1|B_s0|B_s1)

typedef int intx4 __attribute__((ext_vector_type(4)));

#define MFMAI8 __builtin_amdgcn_mfma_i32_16x16x64_i8

// ---------- helpers ----------

// async global->LDS, 16 bytes per lane. LDS side is wave-uniform base + lane*16.
__device__ __forceinline__ void async_copy16(const void* g, void* l) {
    __builtin_amdgcn_global_load_lds(
        (__attribute__((address_space(1))) void*)(g),
        (__attribute__((address_space(3))) void*)(l),
        16, 0, 0);
}

// ---------- pre-pass 1: x fp32 -> int8 per-token (sx = rowmax/127, RNE) ----------

__global__ void quant_x_kernel(const float* __restrict__ in,
                               int8_t* __restrict__ out,
                               float* __restrict__ sx) {
    const int row = blockIdx.x;
    const int tid = threadIdx.x;
    const float4* p = (const float4*)(in + (size_t)row * K_IN + tid * 16);
    float4 v0 = p[0], v1 = p[1], v2 = p[2], v3 = p[3];

    float m = fabsf(v0.x);
    m = fmaxf(m, fabsf(v0.y)); m = fmaxf(m, fabsf(v0.z)); m = fmaxf(m, fabsf(v0.w));
    m = fmaxf(m, fabsf(v1.x)); m = fmaxf(m, fabsf(v1.y));
    m = fmaxf(m, fabsf(v1.z)); m = fmaxf(m, fabsf(v1.w));
    m = fmaxf(m, fabsf(v2.x)); m = fmaxf(m, fabsf(v2.y));
    m = fmaxf(m, fabsf(v2.z)); m = fmaxf(m, fabsf(v2.w));
    m = fmaxf(m, fabsf(v3.x)); m = fmaxf(m, fabsf(v3.y));
    m = fmaxf(m, fabsf(v3.z)); m = fmaxf(m, fabsf(v3.w));

#pragma unroll
    for (int off = 32; off; off >>= 1) m = fmaxf(m, __shfl_xor(m, off));
    __shared__ float wmax[4];
    if ((tid & 63) == 0) wmax[tid >> 6] = m;
    __syncthreads();
    m = fmaxf(fmaxf(wmax[0], wmax[1]), fmaxf(wmax[2], wmax[3]));
    m = fmaxf(m, 1e-20f);

    const float rs = 127.0f / m;
    if (tid == 0) sx[row] = m * (1.0f / 127.0f);

    union { int4 v; int8_t c[16]; } u;
    u.c[0]  = (int8_t)__float2int_rn(v0.x * rs);
    u.c[1]  = (int8_t)__float2int_rn(v0.y * rs);
    u.c[2]  = (int8_t)__float2int_rn(v0.z * rs);
    u.c[3]  = (int8_t)__float2int_rn(v0.w * rs);
    u.c[4]  = (int8_t)__float2int_rn(v1.x * rs);
    u.c[5]  = (int8_t)__float2int_rn(v1.y * rs);
    u.c[6]  = (int8_t)__float2int_rn(v1.z * rs);
    u.c[7]  = (int8_t)__float2int_rn(v1.w * rs);
    u.c[8]  = (int8_t)__float2int_rn(v2.x * rs);
    u.c[9]  = (int8_t)__float2int_rn(v2.y * rs);
    u.c[10] = (int8_t)__float2int_rn(v2.z * rs);
    u.c[11] = (int8_t)__float2int_rn(v2.w * rs);
    u.c[12] = (int8_t)__float2int_rn(v3.x * rs);
    u.c[13] = (int8_t)__float2int_rn(v3.y * rs);
    u.c[14] = (int8_t)__float2int_rn(v3.z * rs);
    u.c[15] = (int8_t)__float2int_rn(v3.w * rs);
    ((int4*)(out + (size_t)row * K_IN))[tid] = u.v;
}

// ---------- pre-pass 2: W int32 (int8-valued) -> int8 pack (EXACT) ----------

__global__ void quant_w_kernel(const int* __restrict__ in,
                               int8_t* __restrict__ out, int n16) {
    int i = blockIdx.x * 256 + threadIdx.x;   // handles 16 elements
    if (i >= n16) return;
    const int4* p = (const int4*)in + (size_t)i * 4;
    int4 a = p[0], b = p[1], c = p[2], d = p[3];
    union { int4 v; int8_t q[16]; } u;
    u.q[0]  = (int8_t)a.x; u.q[1]  = (int8_t)a.y; u.q[2]  = (int8_t)a.z; u.q[3]  = (int8_t)a.w;
    u.q[4]  = (int8_t)b.x; u.q[5]  = (int8_t)b.y; u.q[6]  = (int8_t)b.z; u.q[7]  = (int8_t)b.w;
    u.q[8]  = (int8_t)c.x; u.q[9]  = (int8_t)c.y; u.q[10] = (int8_t)c.z; u.q[11] = (int8_t)c.w;
    u.q[12] = (int8_t)d.x; u.q[13] = (int8_t)d.y; u.q[14] = (int8_t)d.z; u.q[15] = (int8_t)d.w;
    ((int4*)out)[i] = u.v;
}

// ---------- GEMM: C[m][n] = sx[m]*scales[n]*(sum_k xq*wq) + bias[n] ----------
// R6's verified 4-phase single-sync skeleton on i8 / BK=128.
// mfma_i32_16x16x64_i8: A row = lane&15, k = (lane>>4)*16 + j; C/D layout
// dtype-independent (col = lane&15, row = (lane>>4)*4 + reg). Per wave per
// K=128 tile: 24 ds_read_b128 + 64 MFMA. NT = 32.
//
// Ledger (DS in-order per wave; stage = 8 gloads in P1/P2):
//  P1: stage A(t+1) s0,s1 | read A47s0->afB (4) | lgkm(4) [drains prev 8] |
//      MM03(afA,bfA)   [slice s0]
//  P2: stage B(t+1) s0,s1 | read A03s1->afA, Bs1->bfB (8) | lgkm(8) |
//      MM47(afB,bfA)   [s0]
//  P3: read A47s1->afB (4) | lgkm(4) | MM03(afA,bfB)   [s1]
//  P4: vmcnt(0)+lgkm(0) [stages issued 2-3 phases earlier - latency-covered
//      (R16 proved counted vmcnt gains nothing here)] | BARRIER |
//      read A03s0',Bs0' (8, next buf) | MM47(afB,bfB)  [s1]
// Hazards verified: all buf(t) reads lgkm-drained before the boundary
// barrier; stage(t+2) issues after it; buf(t+1) reads follow every wave's
// vmcnt(0)+barrier.
//
// LDS: byte sections A_s0|A_s1|B_s0|B_s1 (16 KiB each = 256 rows x 64 B),
// PAIR-ROW swizzle (HW-verified 0 conflicts): pair p = row>>1 (128 B) holds
// rows {2p,2p+1}; 16 B chunk (p,c): cg = c ^ (p&7); inverse on the per-lane
// GLOBAL source, linear LDS dest. Every ds_read_b128 covers one contiguous
// 1 KiB window exactly once (the R5/R18 lesson).

__global__ __launch_bounds__(512, 2)
void gemm_i8_kernel(const int8_t* __restrict__ A,
                    const int8_t* __restrict__ B,
                    const float* __restrict__ sx,
                    const float* __restrict__ scales,
                    const float* __restrict__ bias,
                    float* __restrict__ C) {
    __shared__ __align__(16) int8_t lds[2 * BUF];   // 128 KiB

    const int tid = threadIdx.x;

    // T1: bijective XCD swizzle (nwg = 512, divisible by 8), bn-fastest.
    const int nwg = (M_TOK / BM) * (N_OUT / BN);   // 32*16 = 512
    const int cpx = nwg / 8;                        // 64
    const int wg  = (blockIdx.x % 8) * cpx + blockIdx.x / 8;
    const int bn  = wg & 15;                        // N_OUT/BN = 16
    const int bm  = wg >> 4;                        // 0..31

    const int lane = tid & 63;
    const int wave = tid >> 6;          // 0..7
    const int wm   = wave >> 2;         // 0..1 -> rows wm*128
    const int wn   = wave & 3;          // 0..3 -> cols wn*64

    // ---- staging addressing (pair-row inverse swizzle, bytes) ----
    // One issue = 512 lanes x 16 B = 8 KiB = 64 pairs = 128 rows of a 64B slice.
    const int t8 = tid >> 3;                        // 0..63
    const int cg = (tid & 7) ^ (t8 & 7);            // unswizzled chunk in pair
    const int grow0 = 2 * t8 + (cg >> 2);           // row within 128-row issue
    const int gcol0 = (cg & 3) * 16;                // bytes within 64B slice
    const int8_t* aP = A + (size_t)(bm * BM + grow0) * K_IN + gcol0;
    const int8_t* bP = B + (size_t)(bn * BN + grow0) * K_IN + gcol0;

    auto stA = [&](int tt, int s) {
        int8_t* d = &lds[(tt & 1) * BUF + s * SEC + tid * 16];
        const int8_t* g = aP + (size_t)tt * BK + s * 64;
        async_copy16(g, d);
        async_copy16(g + (size_t)128 * K_IN, d + 8192);
    };
    auto stB = [&](int tt, int s) {
        int8_t* d = &lds[(tt & 1) * BUF + 2 * SEC + s * SEC + tid * 16];
        const int8_t* g = bP + (size_t)tt * BK + s * 64;
        async_copy16(g, d);
        async_copy16(g + (size_t)128 * K_IN, d + 8192);
    };

    // ---- fragment read addressing ----
    // Frag row R: pair p = R>>1, chunk c = ((R&1)*4 + q) ^ ((R>>1)&7), 16 B.
    const int r16 = lane & 15;
    const int q   = lane >> 4;                      // k-chunk (16 B) in slice
    const int cr  = (((r16 & 1) << 2) + q) ^ ((r16 >> 1) & 7);
    const int aOff = (wm * 64 + (r16 >> 1)) * 128 + cr * 16;
    const int bOff = 2 * SEC + (wn * 32 + (r16 >> 1)) * 128 + cr * 16;

    intx4 acc[8][4] = {};
    intx4 afA[4], afB[4], bfA[4], bfB[4];

#define RD_A03(dst, base, s)                                                   \
    { _Pragma("unroll") for (int i = 0; i < 4; ++i)                            \
        dst[i] = *(const intx4*)((base) + (s) * SEC + aOff + i * 1024); }
#define RD_A47(dst, base, s)                                                   \
    { _Pragma("unroll") for (int i = 0; i < 4; ++i)                            \
        dst[i] = *(const intx4*)((base) + (s) * SEC + aOff + (4 + i) * 1024); }
#define RD_BF(dst, base, s)                                                    \
    { _Pragma("unroll") for (int j = 0; j < 4; ++j)                            \
        dst[j] = *(const intx4*)((base) + (s) * SEC + bOff + j * 1024); }
#define MM03(af, bf)                                                           \
    { __builtin_amdgcn_s_setprio(1);                                           \
      _Pragma("unroll") for (int i = 0; i < 4; ++i)                            \
          _Pragma("unroll") for (int j = 0; j < 4; ++j)                        \
              acc[i][j] = MFMAI8(af[i], bf[j], acc[i][j], 0, 0, 0);            \
      __builtin_amdgcn_s_setprio(0); }
#define MM47(af, bf)                                                           \
    { __builtin_amdgcn_s_setprio(1);                                           \
      _Pragma("unroll") for (int i = 0; i < 4; ++i)                            \
          _Pragma("unroll") for (int j = 0; j < 4; ++j)                        \
              acc[4 + i][j] = MFMAI8(af[i], bf[j], acc[4 + i][j], 0, 0, 0);    \
      __builtin_amdgcn_s_setprio(0); }
#define SBAR __builtin_amdgcn_sched_barrier(0)

    // ---- prologue: stage tile 0, publish, read s0 frags (8 left in flight) ----
    stA(0, 0); stB(0, 0); stA(0, 1); stB(0, 1);
    asm volatile("s_waitcnt vmcnt(0)" ::: "memory");
    __builtin_amdgcn_s_barrier();
    asm volatile("" ::: "memory");
    RD_A03(afA, lds, 0);
    RD_BF(bfA, lds, 0);

#pragma unroll 1
    for (int t = 0; t < NT; ++t) {
        const int8_t* Lb  = lds + (t & 1) * BUF;
        const int8_t* Lb2 = lds + ((t + 1) & 1) * BUF;
        const bool pf = (t + 1 < NT);

        // ---- P1: stage A(t+1) | read A47s0 | MM03(afA,bfA) ----
        if (pf) { stA(t + 1, 0); stA(t + 1, 1); }
        RD_A47(afB, Lb, 0);
        asm volatile("s_waitcnt lgkmcnt(4)" ::: "memory");
        SBAR;
        MM03(afA, bfA);

        // ---- P2: stage B(t+1) | read A03s1, Bs1 | MM47(afB,bfA) ----
        if (pf) { stB(t + 1, 0); stB(t + 1, 1); }
        RD_A03(afA, Lb, 1);
        RD_BF(bfB, Lb, 1);
        asm volatile("s_waitcnt lgkmcnt(8)" ::: "memory");
        SBAR;
        MM47(afB, bfA);

        // ---- P3: read A47s1 | MM03(afA,bfB) ----
        RD_A47(afB, Lb, 1);
        asm volatile("s_waitcnt lgkmcnt(4)" ::: "memory");
        SBAR;
        MM03(afA, bfB);

        // ---- P4: boundary sync | read next s0 frags | MM47(afB,bfB) ----
        asm volatile("s_waitcnt vmcnt(0) lgkmcnt(0)" ::: "memory");
        __builtin_amdgcn_s_barrier();
        asm volatile("" ::: "memory");
        if (pf) {
            RD_A03(afA, Lb2, 0);
            RD_BF(bfA, Lb2, 0);
        }
        SBAR;
        MM47(afB, bfB);
    }

    // ---- epilogue: C/D col = lane&15, row = (lane>>4)*4 + reg (dtype-indep) ----
    const int row0 = bm * BM + wm * 128 + q * 4;
    const int col0 = bn * BN + wn * 64 + r16;
    float sxv[8][4];
#pragma unroll
    for (int fr = 0; fr < 8; ++fr)
#pragma unroll
        for (int r = 0; r < 4; ++r)
            sxv[fr][r] = sx[row0 + fr * 16 + r];
#pragma unroll
    for (int fc = 0; fc < 4; ++fc) {
        const int n  = col0 + fc * 16;
        const float sc = scales[n];
        const float bi = bias[n];
#pragma unroll
        for (int fr = 0; fr < 8; ++fr) {
            const int m = row0 + fr * 16;
#pragma unroll
            for (int r = 0; r < 4; ++r)
                C[(size_t)(m + r) * N_OUT + n] =
                    (float)acc[fr][fc][r] * (sxv[fr][r] * sc) + bi;
        }
    }
}

// ---------- launch ----------

extern "C" void kernel_launch(void* const* d_in, const int* in_sizes, int n_in,
                              void* d_out, int out_size, void* d_ws, size_t ws_size,
                              hipStream_t stream) {
    const float* x      = (const float*)d_in[0];
    const int*   wq     = (const int*)d_in[1];
    const float* scales = (const float*)d_in[2];
    const float* bias   = (const float*)d_in[3];
    float*       out    = (float*)d_out;

    int8_t* xq = (int8_t*)d_ws;                               // 32 MiB
    int8_t* wb = xq + (size_t)M_TOK * K_IN;                   // 16 MiB
    float*  sx = (float*)(wb + (size_t)N_OUT * K_IN);         // 32 KiB
    // ws needed: 48 MiB + 32 KiB

    quant_x_kernel<<<M_TOK, 256, 0, stream>>>(x, xq, sx);
    const int nw16 = (N_OUT * K_IN) / 16;   // 1048576
    quant_w_kernel<<<nw16 / 256, 256, 0, stream>>>(wq, wb, nw16);

    const int grid = (M_TOK / BM) * (N_OUT / BN);   // 32 * 16 = 512
    gemm_i8_kernel<<<grid, 512, 0, stream>>>(xq, wb, sx, scales, bias, out);
}